// Round 16
// baseline (409.497 us; speedup 1.0000x reference)
//
#include <hip/hip_runtime.h>
#include <cstddef>

#define NN   16000          // nodes
#define NE   256000         // edges (without self loops)
#define EP   (NE + NN)      // 272000 with self loops
#define BG   32             // graphs
#define IN_F 768
#define HID  256
#define H1C  4
#define F1   (H1C * HID)    // 1024
#define OUTF 128
#define H2C  2
#define F2   (H2C * OUTF)   // 256

typedef __bf16 bf16x8 __attribute__((ext_vector_type(8)));
typedef float  f32x4  __attribute__((ext_vector_type(4)));
typedef float  f32x2  __attribute__((ext_vector_type(2)));
typedef unsigned short us8 __attribute__((ext_vector_type(8)));

static __device__ __forceinline__ float lrelu02(float x) { return x > 0.f ? x : 0.2f * x; }
static __device__ __forceinline__ float eluf(float x)    { return x > 0.f ? x : expm1f(x); }
static __device__ __forceinline__ unsigned short rne_bf16(float f) {
    unsigned u = __float_as_uint(f);
    return (unsigned short)((u + 0x7fffu + ((u >> 16) & 1u)) >> 16);
}
static __device__ __forceinline__ f32x2 cvt2(unsigned int u) {
    f32x2 r;
    r.x = __uint_as_float(u << 16);
    r.y = __uint_as_float(u & 0xffff0000u);
    return r;
}

#define GLDS16(gp, lp) __builtin_amdgcn_global_load_lds(                         \
    (const __attribute__((address_space(1))) void*)(gp),                          \
    (__attribute__((address_space(3))) void*)(lp), 16, 0, 0)

// ---------------- prep mega-kernel: 3x f2b + hist ----------------
#define NB_X  ((NN * IN_F) / 1024)      // 12000
#define NB_W1 ((F1 * IN_F) / 1024)      // 768
#define NB_W2 ((F2 * F1) / 1024)        // 256
#define NB_H  ((EP + 255) / 256)        // 1063
#define NB_PREP (NB_X + NB_W1 + NB_W2 + NB_H)

static __device__ __forceinline__ void f2b_body(const float* __restrict__ in,
                                                unsigned short* __restrict__ out,
                                                int blk, int t) {
    int i = (blk * 256 + t) * 4;
    float4 v = *(const float4*)&in[i];
    ushort4 o;
    o.x = rne_bf16(v.x); o.y = rne_bf16(v.y); o.z = rne_bf16(v.z); o.w = rne_bf16(v.w);
    *(ushort4*)&out[i] = o;
}

__global__ __launch_bounds__(256) void k_prep(const float* __restrict__ x,
                                              const float* __restrict__ W1,
                                              const float* __restrict__ W2,
                                              unsigned short* __restrict__ xb,
                                              unsigned short* __restrict__ W1b,
                                              unsigned short* __restrict__ W2b,
                                              const int* __restrict__ ei,
                                              int* __restrict__ deg) {
    int b = blockIdx.x, t = threadIdx.x;
    if (b < NB_X) { f2b_body(x, xb, b, t); return; }
    b -= NB_X;
    if (b < NB_W1) { f2b_body(W1, W1b, b, t); return; }
    b -= NB_W1;
    if (b < NB_W2) { f2b_body(W2, W2b, b, t); return; }
    b -= NB_W2;
    int e = b * 256 + t;
    if (e >= EP) return;
    int d = (e < NE) ? ei[NE + e] : (e - NE);
    atomicAdd(&deg[d], 1);
}

__global__ __launch_bounds__(1024) void k_scan(const int* __restrict__ deg,
                                               int* __restrict__ off, int* __restrict__ cursor) {
    __shared__ int sums[1024];
    int t = threadIdx.x;
    const int CH = 16;
    int base = t * CH;
    int s = 0;
    for (int i = 0; i < CH; ++i) { int idx = base + i; if (idx < NN) s += deg[idx]; }
    sums[t] = s;
    __syncthreads();
    for (int ofs = 1; ofs < 1024; ofs <<= 1) {
        int v = 0;
        if (t >= ofs) v = sums[t - ofs];
        __syncthreads();
        sums[t] += v;
        __syncthreads();
    }
    int run = sums[t] - s;
    for (int i = 0; i < CH; ++i) {
        int idx = base + i;
        if (idx < NN) { off[idx] = run; cursor[idx] = run; run += deg[idx]; }
    }
    if (t == 1023) off[NN] = run;
}

// ---------------- BM=64 BN=128 BK=32 bf16 MFMA GEMM body, LDS double-buffered ----------
// As: 2 x 2048 shorts, Bs: 2 x 4096 shorts. One barrier per K-iter; prefetch issued
// after the barrier stays in flight across the MFMA block (true overlap).
template <int KITER, int HSHIFT, int HCNT>
static __device__ __forceinline__ void gemm_body(const unsigned short* __restrict__ A,
                                                 const unsigned short* __restrict__ B,
                                                 unsigned short* __restrict__ C,
                                                 const float* __restrict__ a_s,
                                                 const float* __restrict__ a_d,
                                                 float* __restrict__ as_o,
                                                 float* __restrict__ ad_o,
                                                 int N, int K, int bx, int by,
                                                 unsigned short* As, unsigned short* Bs,
                                                 int t) {
    const int w = t >> 6, lane = t & 63;
    const int m0 = by * 64, n0 = bx * 128;
    const int wm = (w >> 1) * 32, wn = (w & 1) * 64;

    const unsigned short* ga0 = A + (size_t)(m0 + (t >> 2)) * K + (t & 3) * 8;   // 64x32 tile
    const unsigned short* gb0 = B + (size_t)(n0 + (t >> 2)) * K + (t & 3) * 8;   // rows 0..63
    const unsigned short* gb1 = gb0 + (size_t)64 * K;                             // rows 64..127
    unsigned short* lA[2] = { &As[(w * 64) * 8],        &As[2048 + (w * 64) * 8] };
    unsigned short* lB0a[2] = { &Bs[(w * 64) * 8],      &Bs[4096 + (w * 64) * 8] };
    unsigned short* lB1a[2] = { &Bs[(w * 64 + 256) * 8],&Bs[4096 + (w * 64 + 256) * 8] };

    f32x4 acc[2][4] = {};

    const int fo = (wm + (lane & 15)) * 4 + (lane >> 4);

    // prefetch tile 0 -> buffer 0
    GLDS16(ga0, lA[0]); GLDS16(gb0, lB0a[0]); GLDS16(gb1, lB1a[0]);
    ga0 += 32; gb0 += 32; gb1 += 32;

    for (int it = 0; it < KITER; ++it) {
        __syncthreads();                       // tile(it) resident; alt buffer free
        int cur = it & 1;
        if (it + 1 < KITER) {
            int nxt = cur ^ 1;
            GLDS16(ga0, lA[nxt]); GLDS16(gb0, lB0a[nxt]); GLDS16(gb1, lB1a[nxt]);
            ga0 += 32; gb0 += 32; gb1 += 32;   // stays in flight during compute
        }
        const bf16x8* pa = (const bf16x8*)(As + cur * 2048) + fo;
        const bf16x8* pb = (const bf16x8*)(Bs + cur * 4096) + ((wn + (lane & 15)) * 4 + (lane >> 4));
        bf16x8 a0 = pa[0], a1 = pa[64];
        bf16x8 b0 = pb[0], b1 = pb[64], b2 = pb[128], b3 = pb[192];
        acc[0][0] = __builtin_amdgcn_mfma_f32_16x16x32_bf16(a0, b0, acc[0][0], 0, 0, 0);
        acc[0][1] = __builtin_amdgcn_mfma_f32_16x16x32_bf16(a0, b1, acc[0][1], 0, 0, 0);
        acc[0][2] = __builtin_amdgcn_mfma_f32_16x16x32_bf16(a0, b2, acc[0][2], 0, 0, 0);
        acc[0][3] = __builtin_amdgcn_mfma_f32_16x16x32_bf16(a0, b3, acc[0][3], 0, 0, 0);
        acc[1][0] = __builtin_amdgcn_mfma_f32_16x16x32_bf16(a1, b0, acc[1][0], 0, 0, 0);
        acc[1][1] = __builtin_amdgcn_mfma_f32_16x16x32_bf16(a1, b1, acc[1][1], 0, 0, 0);
        acc[1][2] = __builtin_amdgcn_mfma_f32_16x16x32_bf16(a1, b2, acc[1][2], 0, 0, 0);
        acc[1][3] = __builtin_amdgcn_mfma_f32_16x16x32_bf16(a1, b3, acc[1][3], 0, 0, 0);
    }
    const int ccol = n0 + wn + (lane & 15);
    const int crow = m0 + wm + (lane >> 4) * 4;
    // direct C store
#pragma unroll
    for (int mi = 0; mi < 2; ++mi)
#pragma unroll
        for (int i = 0; i < 4; ++i) {
            unsigned short* cp = C + (size_t)(crow + mi * 16 + i) * N + ccol;
            cp[0]  = rne_bf16(acc[mi][0][i]);
            cp[16] = rne_bf16(acc[mi][1][i]);
            cp[32] = rne_bf16(acc[mi][2][i]);
            cp[48] = rne_bf16(acc[mi][3][i]);
        }
    // fused alpha epilogue: head is wave-uniform (block cols lie within one head)
    const int hh = n0 >> HSHIFT;
    float asv[4], adv[4];
#pragma unroll
    for (int bi = 0; bi < 4; ++bi) {
        asv[bi] = a_s[ccol + bi * 16];
        adv[bi] = a_d[ccol + bi * 16];
    }
#pragma unroll
    for (int mi = 0; mi < 2; ++mi)
#pragma unroll
        for (int i = 0; i < 4; ++i) {
            float vs = acc[mi][0][i] * asv[0] + acc[mi][1][i] * asv[1]
                     + acc[mi][2][i] * asv[2] + acc[mi][3][i] * asv[3];
            float vd = acc[mi][0][i] * adv[0] + acc[mi][1][i] * adv[1]
                     + acc[mi][2][i] * adv[2] + acc[mi][3][i] * adv[3];
#pragma unroll
            for (int m = 1; m <= 8; m <<= 1) {
                vs += __shfl_xor(vs, m);
                vd += __shfl_xor(vd, m);
            }
            if ((lane & 15) == 0) {
                int r = crow + mi * 16 + i;
                atomicAdd(&as_o[r * HCNT + hh], vs);
                atomicAdd(&ad_o[r * HCNT + hh], vd);
            }
        }
}

// GEMM1: M=16000/64=250 panels x 8 col-blocks; panel -> blk%8 (XCD swizzle);
// CSR scatter as sequential tail blocks.
#define G1_BLKS 2048
__global__ __launch_bounds__(256) void k_gemm1(const unsigned short* __restrict__ A,
                                               const unsigned short* __restrict__ B,
                                               unsigned short* __restrict__ C,
                                               const float* __restrict__ a_s,
                                               const float* __restrict__ a_d,
                                               float* __restrict__ as_o,
                                               float* __restrict__ ad_o,
                                               const int* __restrict__ ei,
                                               int* __restrict__ cursor,
                                               int* __restrict__ csr_src,
                                               int* __restrict__ csr_dst) {
    __shared__ __align__(16) unsigned short As[4096];
    __shared__ __align__(16) unsigned short Bs[8192];
    int blk = blockIdx.x, t = threadIdx.x;
    if (blk < G1_BLKS) {
        int by = (blk & 7) + 8 * (blk >> 6);      // panel index; same panel -> same blk%8
        int bx = (blk >> 3) & 7;
        if (by < 250)
            gemm_body<24, 8, 4>(A, B, C, a_s, a_d, as_o, ad_o, F1, IN_F, bx, by, As, Bs, t);
        return;
    }
    int e = (blk - G1_BLKS) * 256 + t;
    if (e >= EP) return;
    int s, d;
    if (e < NE) { s = ei[e]; d = ei[NE + e]; } else { s = d = e - NE; }
    int pos = atomicAdd(&cursor[d], 1);
    csr_src[pos] = s;
    csr_dst[pos] = d;
}

__global__ __launch_bounds__(256) void k_gemm2(const unsigned short* __restrict__ A,
                                               const unsigned short* __restrict__ B,
                                               unsigned short* __restrict__ C,
                                               const float* __restrict__ a_s,
                                               const float* __restrict__ a_d,
                                               float* __restrict__ as_o,
                                               float* __restrict__ ad_o) {
    __shared__ __align__(16) unsigned short As[4096];
    __shared__ __align__(16) unsigned short Bs[8192];
    int blk = blockIdx.x, t = threadIdx.x;
    int by = (blk & 7) + 8 * (blk >> 4);
    int bx = (blk >> 3) & 1;
    if (by < 250)
        gemm_body<32, 7, 2>(A, B, C, a_s, a_d, as_o, ad_o, F2, F1, bx, by, As, Bs, t);
}

// ---------------- edge q-values (exp of logits) in CSR order ----------------
__global__ __launch_bounds__(256) void k_el1(const int* __restrict__ csr_src,
                                             const int* __restrict__ csr_dst,
                                             const float* __restrict__ as1,
                                             const float* __restrict__ ad1,
                                             float* __restrict__ el) {
    int j = blockIdx.x * 256 + threadIdx.x;
    if (j >= EP) return;
    int s = csr_src[j], d = csr_dst[j];
    float4 av = *(const float4*)&as1[s * H1C];
    float4 dv = *(const float4*)&ad1[d * H1C];
    float4 o;
    o.x = expf(lrelu02(av.x + dv.x));
    o.y = expf(lrelu02(av.y + dv.y));
    o.z = expf(lrelu02(av.z + dv.z));
    o.w = expf(lrelu02(av.w + dv.w));
    *(float4*)&el[(size_t)j * 4] = o;
}

__global__ __launch_bounds__(256) void k_el2(const int* __restrict__ csr_src,
                                             const int* __restrict__ csr_dst,
                                             const float* __restrict__ as2,
                                             const float* __restrict__ ad2,
                                             float* __restrict__ el) {
    int j = blockIdx.x * 256 + threadIdx.x;
    if (j >= EP) return;
    int s = csr_src[j], d = csr_dst[j];
    float2 av = *(const float2*)&as2[s * 2];
    float2 dv = *(const float2*)&ad2[d * 2];
    float2 o;
    o.x = expf(lrelu02(av.x + dv.x));
    o.y = expf(lrelu02(av.y + dv.y));
    *(float2*)&el[(size_t)j * 2] = o;
}

// ---------------- layer-1: 2 waves/node, q-softmax, packed-FMA gather ----------------
__global__ __launch_bounds__(256) void k_gat1(const unsigned short* __restrict__ hb,
                                              const float* __restrict__ el,
                                              const int* __restrict__ off,
                                              const int* __restrict__ csr,
                                              const float* __restrict__ b1,
                                              unsigned short* __restrict__ h1b) {
    const int l = threadIdx.x & 63;
    const int w = threadIdx.x >> 6;
    const int d = blockIdx.x * 2 + (w >> 1);
    const int hf = w & 1;
    const int beg = off[d], end = off[d + 1];
    const int h = hf * 2 + (l >> 5);
    const int f0 = hf * 512 + l * 8;

    float sA = 0.f, sB = 0.f;
    for (int j = beg + l; j < end; j += 64) {
        float2 e = *(const float2*)&el[(size_t)j * 4 + hf * 2];
        sA += e.x; sB += e.y;
    }
    for (int o = 32; o > 0; o >>= 1) {
        sA += __shfl_down(sA, o);
        sB += __shfl_down(sB, o);
    }
    sA = __shfl(sA, 0); sB = __shfl(sB, 0);
    float rdh = 1.f / (((l < 32) ? sA : sB) + 1e-16f);

    f32x2 acc[4] = {};
    const unsigned int* hbase = (const unsigned int*)hb;
    const int lofs = f0 >> 1;
    for (int cbeg = beg; cbeg < end; cbeg += 32) {
        int cnt = end - cbeg; if (cnt > 32) cnt = 32;
        int idx = cbeg + (l & 31);
        int idxc = idx < end ? idx : end - 1;
        int s_sel = csr[idxc];
        float ev = el[(size_t)idxc * 4 + h];
        float myw = (idx < end) ? ev * rdh : 0.f;
        for (int jj = 0; jj < cnt; jj += 4) {
            int sa = __builtin_amdgcn_readlane(s_sel, jj + 0);
            int sb = __builtin_amdgcn_readlane(s_sel, jj + 1);
            int sc = __builtin_amdgcn_readlane(s_sel, jj + 2);
            int sd = __builtin_amdgcn_readlane(s_sel, jj + 3);
            float wa = __shfl(myw, (l & 32) | (jj + 0));
            float wb = __shfl(myw, (l & 32) | (jj + 1));
            float wc = __shfl(myw, (l & 32) | (jj + 2));
            float wd = __shfl(myw, (l & 32) | (jj + 3));
            uint4 va = *(const uint4*)(hbase + (unsigned)sa * (F1 / 2) + lofs);
            uint4 vb = *(const uint4*)(hbase + (unsigned)sb * (F1 / 2) + lofs);
            uint4 vc = *(const uint4*)(hbase + (unsigned)sc * (F1 / 2) + lofs);
            uint4 vd = *(const uint4*)(hbase + (unsigned)sd * (F1 / 2) + lofs);
            f32x2 wa2 = {wa, wa}, wb2 = {wb, wb}, wc2 = {wc, wc}, wd2 = {wd, wd};
            acc[0] += wa2 * cvt2(va.x); acc[1] += wa2 * cvt2(va.y);
            acc[2] += wa2 * cvt2(va.z); acc[3] += wa2 * cvt2(va.w);
            acc[0] += wb2 * cvt2(vb.x); acc[1] += wb2 * cvt2(vb.y);
            acc[2] += wb2 * cvt2(vb.z); acc[3] += wb2 * cvt2(vb.w);
            acc[0] += wc2 * cvt2(vc.x); acc[1] += wc2 * cvt2(vc.y);
            acc[2] += wc2 * cvt2(vc.z); acc[3] += wc2 * cvt2(vc.w);
            acc[0] += wd2 * cvt2(vd.x); acc[1] += wd2 * cvt2(vd.y);
            acc[2] += wd2 * cvt2(vd.z); acc[3] += wd2 * cvt2(vd.w);
        }
    }
    us8 ob;
#pragma unroll
    for (int i = 0; i < 4; ++i) {
        ob[2 * i]     = rne_bf16(eluf(acc[i].x + b1[f0 + 2 * i]));
        ob[2 * i + 1] = rne_bf16(eluf(acc[i].y + b1[f0 + 2 * i + 1]));
    }
    *(us8*)&h1b[(size_t)d * F1 + f0] = ob;
}

// ---------------- layer-2: wave-per-node, q-softmax, packed-FMA, head-mean ----------------
__global__ __launch_bounds__(256) void k_gat2(const unsigned short* __restrict__ h2b,
                                              const float* __restrict__ el,
                                              const int* __restrict__ off,
                                              const int* __restrict__ csr,
                                              const float* __restrict__ b2,
                                              float* __restrict__ out_h2) {
    const int l = threadIdx.x & 63;
    const int d = blockIdx.x * 4 + (threadIdx.x >> 6);
    const int beg = off[d], end = off[d + 1];
    const int c = l & 31, p = l >> 5;
    const int myhead = c >> 4;
    const int hw = p;

    float s0 = 0.f, s1 = 0.f;
    for (int j = beg + l; j < end; j += 64) {
        float2 e = *(const float2*)&el[(size_t)j * 2];
        s0 += e.x; s1 += e.y;
    }
    for (int o = 32; o > 0; o >>= 1) {
        s0 += __shfl_down(s0, o);
        s1 += __shfl_down(s1, o);
    }
    s0 = __shfl(s0, 0); s1 = __shfl(s1, 0);
    float rdhw = 1.f / ((hw ? s1 : s0) + 1e-16f);

    f32x2 acc[4] = {};
    const unsigned int* base = (const unsigned int*)h2b + c * 4;
    for (int cbeg = beg; cbeg < end; cbeg += 32) {
        int cnt = end - cbeg; if (cnt > 32) cnt = 32;
        int idx = cbeg + c;
        int idxc = idx < end ? idx : end - 1;
        int s_sel = csr[idxc];
        float ev = el[(size_t)idxc * 2 + hw];
        float myw = (idx < end) ? ev * rdhw : 0.f;
        for (int jj = 0; jj < cnt; jj += 8) {
            int e0 = jj + p * 4;
            int sa = __shfl(s_sel, e0 + 0);
            int sb = __shfl(s_sel, e0 + 1);
            int sc = __shfl(s_sel, e0 + 2);
            int sd = __shfl(s_sel, e0 + 3);
            float wa = __shfl(myw, (myhead << 5) | (e0 + 0));
            float wb = __shfl(myw, (myhead << 5) | (e0 + 1));
            float wc = __shfl(myw, (myhead << 5) | (e0 + 2));
            float wd = __shfl(myw, (myhead << 5) | (e0 + 3));
            uint4 va = *(const uint4*)(base + (unsigned)sa * (F2 / 2));
            uint4 vb = *(const uint4*)(base + (unsigned)sb * (F2 / 2));
            uint4 vc = *(const uint4*)(base + (unsigned)sc * (F2 / 2));
            uint4 vd = *(const uint4*)(base + (unsigned)sd * (F2 / 2));
            f32x2 wa2 = {wa, wa}, wb2 = {wb, wb}, wc2 = {wc, wc}, wd2 = {wd, wd};
            acc[0] += wa2 * cvt2(va.x); acc[1] += wa2 * cvt2(va.y);
            acc[2] += wa2 * cvt2(va.z); acc[3] += wa2 * cvt2(va.w);
            acc[0] += wb2 * cvt2(vb.x); acc[1] += wb2 * cvt2(vb.y);
            acc[2] += wb2 * cvt2(vb.z); acc[3] += wb2 * cvt2(vb.w);
            acc[0] += wc2 * cvt2(vc.x); acc[1] += wc2 * cvt2(vc.y);
            acc[2] += wc2 * cvt2(vc.z); acc[3] += wc2 * cvt2(vc.w);
            acc[0] += wd2 * cvt2(vd.x); acc[1] += wd2 * cvt2(vd.y);
            acc[2] += wd2 * cvt2(vd.z); acc[3] += wd2 * cvt2(vd.w);
        }
    }
    float af[8] = {acc[0].x, acc[0].y, acc[1].x, acc[1].y,
                   acc[2].x, acc[2].y, acc[3].x, acc[3].y};
#pragma unroll
    for (int i = 0; i < 8; ++i) af[i] += __shfl(af[i], l ^ 32);
    float pt[8];
#pragma unroll
    for (int i = 0; i < 8; ++i) pt[i] = __shfl(af[i], l ^ 16);
    if (l < 16) {
        int f = l * 8;
        float o[8];
#pragma unroll
        for (int i = 0; i < 8; ++i) o[i] = eluf(0.5f * (af[i] + pt[i]) + b2[f + i]);
        *(float4*)&out_h2[(size_t)d * OUTF + f]     = make_float4(o[0], o[1], o[2], o[3]);
        *(float4*)&out_h2[(size_t)d * OUTF + f + 4] = make_float4(o[4], o[5], o[6], o[7]);
    }
}

// ---------------- pool (sorted batch) + projection + LayerNorm ----------------
__global__ __launch_bounds__(1024) void k_proj_ln(const float* __restrict__ h2,
                                                  const int* __restrict__ batch,
                                                  const float* __restrict__ pW,
                                                  const float* __restrict__ pb,
                                                  const float* __restrict__ g,
                                                  const float* __restrict__ be,
                                                  float* __restrict__ out) {
    __shared__ float part[1024];
    __shared__ float ph[OUTF];
    __shared__ float zb[768];
    __shared__ float red[1024];
    __shared__ float s_mu, s_rstd;
    int b = blockIdx.x, t = threadIdx.x;
    int lo = 0, hi = NN;
    while (lo < hi) { int mid = (lo + hi) >> 1; if (batch[mid] < b) lo = mid + 1; else hi = mid; }
    int n0 = lo;
    lo = 0; hi = NN;
    while (lo < hi) { int mid = (lo + hi) >> 1; if (batch[mid] < b + 1) lo = mid + 1; else hi = mid; }
    int n1 = lo;
    {
        int f = t & 127, slot = t >> 7;
        float a = 0.f;
        for (int n = n0 + slot; n < n1; n += 8) a += h2[(size_t)n * OUTF + f];
        part[t] = a;
    }
    __syncthreads();
    if (t < OUTF) {
        float s = 0.f;
#pragma unroll
        for (int k = 0; k < 8; ++k) s += part[k * 128 + t];
        float c = (float)(n1 - n0);
        c = c < 1.f ? 1.f : c;
        ph[t] = s / c;
    }
    __syncthreads();
    if (t < 768) {
        float acc = pb[t];
        for (int k = 0; k < OUTF; k += 4) {
            float4 w = *(const float4*)&pW[(size_t)t * OUTF + k];
            acc += w.x * ph[k] + w.y * ph[k + 1] + w.z * ph[k + 2] + w.w * ph[k + 3];
        }
        zb[t] = acc;
    }
    __syncthreads();
    red[t] = (t < 768) ? zb[t] : 0.f;
    __syncthreads();
    for (int ofs = 512; ofs > 0; ofs >>= 1) {
        if (t < ofs) red[t] += red[t + ofs];
        __syncthreads();
    }
    if (t == 0) s_mu = red[0] / 768.f;
    __syncthreads();
    float mu = s_mu;
    float dv = (t < 768) ? (zb[t] - mu) : 0.f;
    red[t] = dv * dv;
    __syncthreads();
    for (int ofs = 512; ofs > 0; ofs >>= 1) {
        if (t < ofs) red[t] += red[t + ofs];
        __syncthreads();
    }
    if (t == 0) s_rstd = rsqrtf(red[0] / 768.f + 1e-5f);
    __syncthreads();
    float rstd = s_rstd;
    if (t < 768)
        out[(size_t)b * 768 + t] = (zb[t] - mu) * rstd * g[t] + be[t];
}

extern "C" void kernel_launch(void* const* d_in, const int* in_sizes, int n_in,
                              void* d_out, int out_size, void* d_ws, size_t ws_size,
                              hipStream_t stream) {
    const float* x    = (const float*)d_in[0];
    const int*   ei   = (const int*)d_in[1];
    const int*   batch= (const int*)d_in[2];
    const float* W1   = (const float*)d_in[3];
    const float* a1s  = (const float*)d_in[4];
    const float* a1d  = (const float*)d_in[5];
    const float* b1   = (const float*)d_in[6];
    const float* W2   = (const float*)d_in[7];
    const float* a2s  = (const float*)d_in[8];
    const float* a2d  = (const float*)d_in[9];
    const float* b2   = (const float*)d_in[10];
    const float* pW   = (const float*)d_in[11];
    const float* pb   = (const float*)d_in[12];
    const float* lng  = (const float*)d_in[13];
    const float* lnb  = (const float*)d_in[14];

    float* out_ge = (float*)d_out;                 // (32, 768)
    float* out_h2 = (float*)d_out + BG * 768;      // (16000, 128)

    char* w = (char*)d_ws;
    unsigned short* xb   = (unsigned short*)w;  w += (size_t)NN * IN_F * 2;
    unsigned short* W1b  = (unsigned short*)w;  w += (size_t)F1 * IN_F * 2;
    unsigned short* W2b  = (unsigned short*)w;  w += (size_t)F2 * F1 * 2;
    unsigned short* hbufb= (unsigned short*)w;  w += (size_t)NN * F1 * 2;
    unsigned short* h1b  = (unsigned short*)w;  w += (size_t)NN * F1 * 2;
    unsigned short* h2b  = (unsigned short*)w;  w += (size_t)NN * F2 * 2;
    // zeroed region: as1, ad1, as2, ad2, deg (contiguous, one memset)
    float* as1  = (float*)w;  w += (size_t)NN * H1C * 4;
    float* ad1  = (float*)w;  w += (size_t)NN * H1C * 4;
    float* as2  = (float*)w;  w += (size_t)NN * H2C * 4;
    float* ad2  = (float*)w;  w += (size_t)NN * H2C * 4;
    int* deg    = (int*)w;    w += (size_t)NN * 4;
    int* off    = (int*)w;    w += (size_t)(NN + 4) * 4;
    int* cursor = (int*)w;    w += (size_t)NN * 4;
    int* csr    = (int*)w;    w += (size_t)EP * 4;
    int* csrd   = (int*)w;    w += (size_t)EP * 4;
    float* el1  = (float*)w;  w += (size_t)EP * H1C * 4;
    float* el2  = (float*)w;  w += (size_t)EP * H2C * 4;

    hipMemsetAsync(as1, 0, (size_t)NN * (H1C + H1C + H2C + H2C + 1) * 4, stream);

    k_prep<<<NB_PREP, 256, 0, stream>>>(x, W1, W2, xb, W1b, W2b, ei, deg);
    k_scan<<<1, 1024, 0, stream>>>(deg, off, cursor);

    // GEMM1 (+ alpha1 epilogue) + CSR scatter as sequential tail blocks
    k_gemm1<<<G1_BLKS + NB_H, 256, 0, stream>>>(xb, W1b, hbufb, a1s, a1d, as1, ad1,
                                                ei, cursor, csr, csrd);
    k_el1<<<(EP + 255) / 256, 256, 0, stream>>>(csr, csrd, as1, ad1, el1);
    k_gat1<<<NN / 2, 256, 0, stream>>>(hbufb, el1, off, csr, b1, h1b);

    // GEMM2 (+ alpha2 epilogue), XCD-swizzled grid
    k_gemm2<<<512, 256, 0, stream>>>(h1b, W2b, h2b, a2s, a2d, as2, ad2);
    k_el2<<<(EP + 255) / 256, 256, 0, stream>>>(csr, csrd, as2, ad2, el2);
    k_gat2<<<NN / 4, 256, 0, stream>>>(h2b, el2, off, csr, b2, out_h2);

    k_proj_ln<<<BG, 1024, 0, stream>>>(out_h2, batch, pW, pb, lng, lnb, out_ge);
}

// Round 17
// 400.393 us; speedup vs baseline: 1.0227x; 1.0227x over previous
//
#include <hip/hip_runtime.h>
#include <cstddef>

#define NN   16000          // nodes
#define NE   256000         // edges (without self loops)
#define EP   (NE + NN)      // 272000 with self loops
#define BG   32             // graphs
#define IN_F 768
#define HID  256
#define H1C  4
#define F1   (H1C * HID)    // 1024
#define OUTF 128
#define H2C  2
#define F2   (H2C * OUTF)   // 256

typedef __bf16 bf16x8 __attribute__((ext_vector_type(8)));
typedef float  f32x4  __attribute__((ext_vector_type(4)));
typedef float  f32x2  __attribute__((ext_vector_type(2)));
typedef unsigned short us8 __attribute__((ext_vector_type(8)));

static __device__ __forceinline__ float lrelu02(float x) { return x > 0.f ? x : 0.2f * x; }
static __device__ __forceinline__ float eluf(float x)    { return x > 0.f ? x : expm1f(x); }
static __device__ __forceinline__ unsigned short rne_bf16(float f) {
    unsigned u = __float_as_uint(f);
    return (unsigned short)((u + 0x7fffu + ((u >> 16) & 1u)) >> 16);
}
static __device__ __forceinline__ f32x2 cvt2(unsigned int u) {
    f32x2 r;
    r.x = __uint_as_float(u << 16);
    r.y = __uint_as_float(u & 0xffff0000u);
    return r;
}

#define GLDS16(gp, lp) __builtin_amdgcn_global_load_lds(                         \
    (const __attribute__((address_space(1))) void*)(gp),                          \
    (__attribute__((address_space(3))) void*)(lp), 16, 0, 0)

// ---------------- prep mega-kernel: 3x f2b + hist ----------------
#define NB_X  ((NN * IN_F) / 1024)      // 12000
#define NB_W1 ((F1 * IN_F) / 1024)      // 768
#define NB_W2 ((F2 * F1) / 1024)        // 256
#define NB_H  ((EP + 255) / 256)        // 1063
#define NB_PREP (NB_X + NB_W1 + NB_W2 + NB_H)

static __device__ __forceinline__ void f2b_body(const float* __restrict__ in,
                                                unsigned short* __restrict__ out,
                                                int blk, int t) {
    int i = (blk * 256 + t) * 4;
    float4 v = *(const float4*)&in[i];
    ushort4 o;
    o.x = rne_bf16(v.x); o.y = rne_bf16(v.y); o.z = rne_bf16(v.z); o.w = rne_bf16(v.w);
    *(ushort4*)&out[i] = o;
}

__global__ __launch_bounds__(256) void k_prep(const float* __restrict__ x,
                                              const float* __restrict__ W1,
                                              const float* __restrict__ W2,
                                              unsigned short* __restrict__ xb,
                                              unsigned short* __restrict__ W1b,
                                              unsigned short* __restrict__ W2b,
                                              const int* __restrict__ ei,
                                              int* __restrict__ deg) {
    int b = blockIdx.x, t = threadIdx.x;
    if (b < NB_X) { f2b_body(x, xb, b, t); return; }
    b -= NB_X;
    if (b < NB_W1) { f2b_body(W1, W1b, b, t); return; }
    b -= NB_W1;
    if (b < NB_W2) { f2b_body(W2, W2b, b, t); return; }
    b -= NB_W2;
    int e = b * 256 + t;
    if (e >= EP) return;
    int d = (e < NE) ? ei[NE + e] : (e - NE);
    atomicAdd(&deg[d], 1);
}

__global__ __launch_bounds__(1024) void k_scan(const int* __restrict__ deg,
                                               int* __restrict__ off, int* __restrict__ cursor) {
    __shared__ int sums[1024];
    int t = threadIdx.x;
    const int CH = 16;
    int base = t * CH;
    int s = 0;
    for (int i = 0; i < CH; ++i) { int idx = base + i; if (idx < NN) s += deg[idx]; }
    sums[t] = s;
    __syncthreads();
    for (int ofs = 1; ofs < 1024; ofs <<= 1) {
        int v = 0;
        if (t >= ofs) v = sums[t - ofs];
        __syncthreads();
        sums[t] += v;
        __syncthreads();
    }
    int run = sums[t] - s;
    for (int i = 0; i < CH; ++i) {
        int idx = base + i;
        if (idx < NN) { off[idx] = run; cursor[idx] = run; run += deg[idx]; }
    }
    if (t == 1023) off[NN] = run;
}

// ---------------- BM=64 BN=128 BK=32 bf16 MFMA GEMM body, fused alpha ----------
// 4 waves in 2x2: wave (wr,wc) computes rows [wr*32,+32) x cols [wc*64,+64).
// LDS: As 64x32 (4KB, 1 granule round), Bs 128x32 (8KB, 2 rounds).
template <int KITER, int HSHIFT, int HCNT>
static __device__ __forceinline__ void gemm_body(const unsigned short* __restrict__ A,
                                                 const unsigned short* __restrict__ B,
                                                 unsigned short* __restrict__ C,
                                                 const float* __restrict__ a_s,
                                                 const float* __restrict__ a_d,
                                                 float* __restrict__ as_o,
                                                 float* __restrict__ ad_o,
                                                 int N, int K, int bx, int by,
                                                 unsigned short* As, unsigned short* Bs,
                                                 int t) {
    const int w = t >> 6, lane = t & 63;
    const int m0 = by * 64, n0 = bx * 128;
    const int wm = (w >> 1) * 32, wn = (w & 1) * 64;

    const unsigned short* ga0 = A + (size_t)(m0 + (t >> 2)) * K + (t & 3) * 8;   // 64x32 tile
    const unsigned short* gb0 = B + (size_t)(n0 + (t >> 2)) * K + (t & 3) * 8;   // rows 0..63
    const unsigned short* gb1 = gb0 + (size_t)64 * K;                             // rows 64..127
    unsigned short* lA0 = &As[(w * 64) * 8];
    unsigned short* lB0 = &Bs[(w * 64) * 8];
    unsigned short* lB1 = &Bs[(w * 64 + 256) * 8];

    f32x4 acc[2][4] = {};

    const bf16x8* pa = (const bf16x8*)As + (wm + (lane & 15)) * 4 + (lane >> 4);
    const bf16x8* pb = (const bf16x8*)Bs + (wn + (lane & 15)) * 4 + (lane >> 4);

    for (int it = 0; it < KITER; ++it) {
        GLDS16(ga0, lA0);
        GLDS16(gb0, lB0); GLDS16(gb1, lB1);
        ga0 += 32; gb0 += 32; gb1 += 32;
        __syncthreads();
        bf16x8 a0 = pa[0], a1 = pa[64];
        bf16x8 b0 = pb[0], b1 = pb[64], b2 = pb[128], b3 = pb[192];
        acc[0][0] = __builtin_amdgcn_mfma_f32_16x16x32_bf16(a0, b0, acc[0][0], 0, 0, 0);
        acc[0][1] = __builtin_amdgcn_mfma_f32_16x16x32_bf16(a0, b1, acc[0][1], 0, 0, 0);
        acc[0][2] = __builtin_amdgcn_mfma_f32_16x16x32_bf16(a0, b2, acc[0][2], 0, 0, 0);
        acc[0][3] = __builtin_amdgcn_mfma_f32_16x16x32_bf16(a0, b3, acc[0][3], 0, 0, 0);
        acc[1][0] = __builtin_amdgcn_mfma_f32_16x16x32_bf16(a1, b0, acc[1][0], 0, 0, 0);
        acc[1][1] = __builtin_amdgcn_mfma_f32_16x16x32_bf16(a1, b1, acc[1][1], 0, 0, 0);
        acc[1][2] = __builtin_amdgcn_mfma_f32_16x16x32_bf16(a1, b2, acc[1][2], 0, 0, 0);
        acc[1][3] = __builtin_amdgcn_mfma_f32_16x16x32_bf16(a1, b3, acc[1][3], 0, 0, 0);
        __syncthreads();
    }
    const int ccol = n0 + wn + (lane & 15);
    const int crow = m0 + wm + (lane >> 4) * 4;
    // direct C store
#pragma unroll
    for (int mi = 0; mi < 2; ++mi)
#pragma unroll
        for (int i = 0; i < 4; ++i) {
            unsigned short* cp = C + (size_t)(crow + mi * 16 + i) * N + ccol;
            cp[0]  = rne_bf16(acc[mi][0][i]);
            cp[16] = rne_bf16(acc[mi][1][i]);
            cp[32] = rne_bf16(acc[mi][2][i]);
            cp[48] = rne_bf16(acc[mi][3][i]);
        }
    // fused alpha epilogue: head is wave-uniform (block cols lie within one head)
    const int hh = n0 >> HSHIFT;
    float asv[4], adv[4];
#pragma unroll
    for (int bi = 0; bi < 4; ++bi) {
        asv[bi] = a_s[ccol + bi * 16];
        adv[bi] = a_d[ccol + bi * 16];
    }
#pragma unroll
    for (int mi = 0; mi < 2; ++mi)
#pragma unroll
        for (int i = 0; i < 4; ++i) {
            float vs = acc[mi][0][i] * asv[0] + acc[mi][1][i] * asv[1]
                     + acc[mi][2][i] * asv[2] + acc[mi][3][i] * asv[3];
            float vd = acc[mi][0][i] * adv[0] + acc[mi][1][i] * adv[1]
                     + acc[mi][2][i] * adv[2] + acc[mi][3][i] * adv[3];
#pragma unroll
            for (int m = 1; m <= 8; m <<= 1) {
                vs += __shfl_xor(vs, m);
                vd += __shfl_xor(vd, m);
            }
            if ((lane & 15) == 0) {
                int r = crow + mi * 16 + i;
                atomicAdd(&as_o[r * HCNT + hh], vs);
                atomicAdd(&ad_o[r * HCNT + hh], vd);
            }
        }
}

// GEMM1: M=16000/64=250 panels x 8 col-blocks; panel -> blk%8 (XCD swizzle);
// CSR scatter as sequential tail blocks.
#define G1_BLKS 2048
__global__ __launch_bounds__(256) void k_gemm1(const unsigned short* __restrict__ A,
                                               const unsigned short* __restrict__ B,
                                               unsigned short* __restrict__ C,
                                               const float* __restrict__ a_s,
                                               const float* __restrict__ a_d,
                                               float* __restrict__ as_o,
                                               float* __restrict__ ad_o,
                                               const int* __restrict__ ei,
                                               int* __restrict__ cursor,
                                               int* __restrict__ csr_src,
                                               int* __restrict__ csr_dst) {
    __shared__ __align__(16) unsigned short As[2048];
    __shared__ __align__(16) unsigned short Bs[4096];
    int blk = blockIdx.x, t = threadIdx.x;
    if (blk < G1_BLKS) {
        int by = (blk & 7) + 8 * (blk >> 6);      // panel index; same panel -> same blk%8
        int bx = (blk >> 3) & 7;
        if (by < 250)
            gemm_body<24, 8, 4>(A, B, C, a_s, a_d, as_o, ad_o, F1, IN_F, bx, by, As, Bs, t);
        return;
    }
    int e = (blk - G1_BLKS) * 256 + t;
    if (e >= EP) return;
    int s, d;
    if (e < NE) { s = ei[e]; d = ei[NE + e]; } else { s = d = e - NE; }
    int pos = atomicAdd(&cursor[d], 1);
    csr_src[pos] = s;
    csr_dst[pos] = d;
}

__global__ __launch_bounds__(256) void k_gemm2(const unsigned short* __restrict__ A,
                                               const unsigned short* __restrict__ B,
                                               unsigned short* __restrict__ C,
                                               const float* __restrict__ a_s,
                                               const float* __restrict__ a_d,
                                               float* __restrict__ as_o,
                                               float* __restrict__ ad_o) {
    __shared__ __align__(16) unsigned short As[2048];
    __shared__ __align__(16) unsigned short Bs[4096];
    int blk = blockIdx.x, t = threadIdx.x;
    int by = (blk & 7) + 8 * (blk >> 4);
    int bx = (blk >> 3) & 1;
    if (by < 250)
        gemm_body<32, 7, 2>(A, B, C, a_s, a_d, as_o, ad_o, F2, F1, bx, by, As, Bs, t);
}

// ---------------- edge q-values (exp of logits) in CSR order ----------------
__global__ __launch_bounds__(256) void k_el1(const int* __restrict__ csr_src,
                                             const int* __restrict__ csr_dst,
                                             const float* __restrict__ as1,
                                             const float* __restrict__ ad1,
                                             float* __restrict__ el) {
    int j = blockIdx.x * 256 + threadIdx.x;
    if (j >= EP) return;
    int s = csr_src[j], d = csr_dst[j];
    float4 av = *(const float4*)&as1[s * H1C];
    float4 dv = *(const float4*)&ad1[d * H1C];
    float4 o;
    o.x = expf(lrelu02(av.x + dv.x));
    o.y = expf(lrelu02(av.y + dv.y));
    o.z = expf(lrelu02(av.z + dv.z));
    o.w = expf(lrelu02(av.w + dv.w));
    *(float4*)&el[(size_t)j * 4] = o;
}

__global__ __launch_bounds__(256) void k_el2(const int* __restrict__ csr_src,
                                             const int* __restrict__ csr_dst,
                                             const float* __restrict__ as2,
                                             const float* __restrict__ ad2,
                                             float* __restrict__ el) {
    int j = blockIdx.x * 256 + threadIdx.x;
    if (j >= EP) return;
    int s = csr_src[j], d = csr_dst[j];
    float2 av = *(const float2*)&as2[s * 2];
    float2 dv = *(const float2*)&ad2[d * 2];
    float2 o;
    o.x = expf(lrelu02(av.x + dv.x));
    o.y = expf(lrelu02(av.y + dv.y));
    *(float2*)&el[(size_t)j * 2] = o;
}

// ---------------- layer-1: 2 waves/node, q-softmax, packed-FMA gather ----------------
__global__ __launch_bounds__(256) void k_gat1(const unsigned short* __restrict__ hb,
                                              const float* __restrict__ el,
                                              const int* __restrict__ off,
                                              const int* __restrict__ csr,
                                              const float* __restrict__ b1,
                                              unsigned short* __restrict__ h1b) {
    const int l = threadIdx.x & 63;
    const int w = threadIdx.x >> 6;
    const int d = blockIdx.x * 2 + (w >> 1);
    const int hf = w & 1;
    const int beg = off[d], end = off[d + 1];
    const int h = hf * 2 + (l >> 5);
    const int f0 = hf * 512 + l * 8;

    float sA = 0.f, sB = 0.f;
    for (int j = beg + l; j < end; j += 64) {
        float2 e = *(const float2*)&el[(size_t)j * 4 + hf * 2];
        sA += e.x; sB += e.y;
    }
    for (int o = 32; o > 0; o >>= 1) {
        sA += __shfl_down(sA, o);
        sB += __shfl_down(sB, o);
    }
    sA = __shfl(sA, 0); sB = __shfl(sB, 0);
    float rdh = 1.f / (((l < 32) ? sA : sB) + 1e-16f);

    f32x2 acc[4] = {};
    const unsigned int* hbase = (const unsigned int*)hb;
    const int lofs = f0 >> 1;
    for (int cbeg = beg; cbeg < end; cbeg += 32) {
        int cnt = end - cbeg; if (cnt > 32) cnt = 32;
        int idx = cbeg + (l & 31);
        int idxc = idx < end ? idx : end - 1;
        int s_sel = csr[idxc];
        float ev = el[(size_t)idxc * 4 + h];
        float myw = (idx < end) ? ev * rdh : 0.f;
        for (int jj = 0; jj < cnt; jj += 4) {
            int sa = __builtin_amdgcn_readlane(s_sel, jj + 0);
            int sb = __builtin_amdgcn_readlane(s_sel, jj + 1);
            int sc = __builtin_amdgcn_readlane(s_sel, jj + 2);
            int sd = __builtin_amdgcn_readlane(s_sel, jj + 3);
            float wa = __shfl(myw, (l & 32) | (jj + 0));
            float wb = __shfl(myw, (l & 32) | (jj + 1));
            float wc = __shfl(myw, (l & 32) | (jj + 2));
            float wd = __shfl(myw, (l & 32) | (jj + 3));
            uint4 va = *(const uint4*)(hbase + (unsigned)sa * (F1 / 2) + lofs);
            uint4 vb = *(const uint4*)(hbase + (unsigned)sb * (F1 / 2) + lofs);
            uint4 vc = *(const uint4*)(hbase + (unsigned)sc * (F1 / 2) + lofs);
            uint4 vd = *(const uint4*)(hbase + (unsigned)sd * (F1 / 2) + lofs);
            f32x2 wa2 = {wa, wa}, wb2 = {wb, wb}, wc2 = {wc, wc}, wd2 = {wd, wd};
            acc[0] += wa2 * cvt2(va.x); acc[1] += wa2 * cvt2(va.y);
            acc[2] += wa2 * cvt2(va.z); acc[3] += wa2 * cvt2(va.w);
            acc[0] += wb2 * cvt2(vb.x); acc[1] += wb2 * cvt2(vb.y);
            acc[2] += wb2 * cvt2(vb.z); acc[3] += wb2 * cvt2(vb.w);
            acc[0] += wc2 * cvt2(vc.x); acc[1] += wc2 * cvt2(vc.y);
            acc[2] += wc2 * cvt2(vc.z); acc[3] += wc2 * cvt2(vc.w);
            acc[0] += wd2 * cvt2(vd.x); acc[1] += wd2 * cvt2(vd.y);
            acc[2] += wd2 * cvt2(vd.z); acc[3] += wd2 * cvt2(vd.w);
        }
    }
    us8 ob;
#pragma unroll
    for (int i = 0; i < 4; ++i) {
        ob[2 * i]     = rne_bf16(eluf(acc[i].x + b1[f0 + 2 * i]));
        ob[2 * i + 1] = rne_bf16(eluf(acc[i].y + b1[f0 + 2 * i + 1]));
    }
    *(us8*)&h1b[(size_t)d * F1 + f0] = ob;
}

// ---------------- layer-2: wave-per-node, q-softmax, packed-FMA, head-mean ----------------
__global__ __launch_bounds__(256) void k_gat2(const unsigned short* __restrict__ h2b,
                                              const float* __restrict__ el,
                                              const int* __restrict__ off,
                                              const int* __restrict__ csr,
                                              const float* __restrict__ b2,
                                              float* __restrict__ out_h2) {
    const int l = threadIdx.x & 63;
    const int d = blockIdx.x * 4 + (threadIdx.x >> 6);
    const int beg = off[d], end = off[d + 1];
    const int c = l & 31, p = l >> 5;
    const int myhead = c >> 4;
    const int hw = p;

    float s0 = 0.f, s1 = 0.f;
    for (int j = beg + l; j < end; j += 64) {
        float2 e = *(const float2*)&el[(size_t)j * 2];
        s0 += e.x; s1 += e.y;
    }
    for (int o = 32; o > 0; o >>= 1) {
        s0 += __shfl_down(s0, o);
        s1 += __shfl_down(s1, o);
    }
    s0 = __shfl(s0, 0); s1 = __shfl(s1, 0);
    float rdhw = 1.f / ((hw ? s1 : s0) + 1e-16f);

    f32x2 acc[4] = {};
    const unsigned int* base = (const unsigned int*)h2b + c * 4;
    for (int cbeg = beg; cbeg < end; cbeg += 32) {
        int cnt = end - cbeg; if (cnt > 32) cnt = 32;
        int idx = cbeg + c;
        int idxc = idx < end ? idx : end - 1;
        int s_sel = csr[idxc];
        float ev = el[(size_t)idxc * 2 + hw];
        float myw = (idx < end) ? ev * rdhw : 0.f;
        for (int jj = 0; jj < cnt; jj += 8) {
            int e0 = jj + p * 4;
            int sa = __shfl(s_sel, e0 + 0);
            int sb = __shfl(s_sel, e0 + 1);
            int sc = __shfl(s_sel, e0 + 2);
            int sd = __shfl(s_sel, e0 + 3);
            float wa = __shfl(myw, (myhead << 5) | (e0 + 0));
            float wb = __shfl(myw, (myhead << 5) | (e0 + 1));
            float wc = __shfl(myw, (myhead << 5) | (e0 + 2));
            float wd = __shfl(myw, (myhead << 5) | (e0 + 3));
            uint4 va = *(const uint4*)(base + (unsigned)sa * (F2 / 2));
            uint4 vb = *(const uint4*)(base + (unsigned)sb * (F2 / 2));
            uint4 vc = *(const uint4*)(base + (unsigned)sc * (F2 / 2));
            uint4 vd = *(const uint4*)(base + (unsigned)sd * (F2 / 2));
            f32x2 wa2 = {wa, wa}, wb2 = {wb, wb}, wc2 = {wc, wc}, wd2 = {wd, wd};
            acc[0] += wa2 * cvt2(va.x); acc[1] += wa2 * cvt2(va.y);
            acc[2] += wa2 * cvt2(va.z); acc[3] += wa2 * cvt2(va.w);
            acc[0] += wb2 * cvt2(vb.x); acc[1] += wb2 * cvt2(vb.y);
            acc[2] += wb2 * cvt2(vb.z); acc[3] += wb2 * cvt2(vb.w);
            acc[0] += wc2 * cvt2(vc.x); acc[1] += wc2 * cvt2(vc.y);
            acc[2] += wc2 * cvt2(vc.z); acc[3] += wc2 * cvt2(vc.w);
            acc[0] += wd2 * cvt2(vd.x); acc[1] += wd2 * cvt2(vd.y);
            acc[2] += wd2 * cvt2(vd.z); acc[3] += wd2 * cvt2(vd.w);
        }
    }
    float af[8] = {acc[0].x, acc[0].y, acc[1].x, acc[1].y,
                   acc[2].x, acc[2].y, acc[3].x, acc[3].y};
#pragma unroll
    for (int i = 0; i < 8; ++i) af[i] += __shfl(af[i], l ^ 32);
    float pt[8];
#pragma unroll
    for (int i = 0; i < 8; ++i) pt[i] = __shfl(af[i], l ^ 16);
    if (l < 16) {
        int f = l * 8;
        float o[8];
#pragma unroll
        for (int i = 0; i < 8; ++i) o[i] = eluf(0.5f * (af[i] + pt[i]) + b2[f + i]);
        *(float4*)&out_h2[(size_t)d * OUTF + f]     = make_float4(o[0], o[1], o[2], o[3]);
        *(float4*)&out_h2[(size_t)d * OUTF + f + 4] = make_float4(o[4], o[5], o[6], o[7]);
    }
}

// ---------------- pool (sorted batch) + projection + LayerNorm ----------------
__global__ __launch_bounds__(1024) void k_proj_ln(const float* __restrict__ h2,
                                                  const int* __restrict__ batch,
                                                  const float* __restrict__ pW,
                                                  const float* __restrict__ pb,
                                                  const float* __restrict__ g,
                                                  const float* __restrict__ be,
                                                  float* __restrict__ out) {
    __shared__ float part[1024];
    __shared__ float ph[OUTF];
    __shared__ float zb[768];
    __shared__ float red[1024];
    __shared__ float s_mu, s_rstd;
    int b = blockIdx.x, t = threadIdx.x;
    int lo = 0, hi = NN;
    while (lo < hi) { int mid = (lo + hi) >> 1; if (batch[mid] < b) lo = mid + 1; else hi = mid; }
    int n0 = lo;
    lo = 0; hi = NN;
    while (lo < hi) { int mid = (lo + hi) >> 1; if (batch[mid] < b + 1) lo = mid + 1; else hi = mid; }
    int n1 = lo;
    {
        int f = t & 127, slot = t >> 7;
        float a = 0.f;
        for (int n = n0 + slot; n < n1; n += 8) a += h2[(size_t)n * OUTF + f];
        part[t] = a;
    }
    __syncthreads();
    if (t < OUTF) {
        float s = 0.f;
#pragma unroll
        for (int k = 0; k < 8; ++k) s += part[k * 128 + t];
        float c = (float)(n1 - n0);
        c = c < 1.f ? 1.f : c;
        ph[t] = s / c;
    }
    __syncthreads();
    if (t < 768) {
        float acc = pb[t];
        for (int k = 0; k < OUTF; k += 4) {
            float4 w = *(const float4*)&pW[(size_t)t * OUTF + k];
            acc += w.x * ph[k] + w.y * ph[k + 1] + w.z * ph[k + 2] + w.w * ph[k + 3];
        }
        zb[t] = acc;
    }
    __syncthreads();
    red[t] = (t < 768) ? zb[t] : 0.f;
    __syncthreads();
    for (int ofs = 512; ofs > 0; ofs >>= 1) {
        if (t < ofs) red[t] += red[t + ofs];
        __syncthreads();
    }
    if (t == 0) s_mu = red[0] / 768.f;
    __syncthreads();
    float mu = s_mu;
    float dv = (t < 768) ? (zb[t] - mu) : 0.f;
    red[t] = dv * dv;
    __syncthreads();
    for (int ofs = 512; ofs > 0; ofs >>= 1) {
        if (t < ofs) red[t] += red[t + ofs];
        __syncthreads();
    }
    if (t == 0) s_rstd = rsqrtf(red[0] / 768.f + 1e-5f);
    __syncthreads();
    float rstd = s_rstd;
    if (t < 768)
        out[(size_t)b * 768 + t] = (zb[t] - mu) * rstd * g[t] + be[t];
}

extern "C" void kernel_launch(void* const* d_in, const int* in_sizes, int n_in,
                              void* d_out, int out_size, void* d_ws, size_t ws_size,
                              hipStream_t stream) {
    const float* x    = (const float*)d_in[0];
    const int*   ei   = (const int*)d_in[1];
    const int*   batch= (const int*)d_in[2];
    const float* W1   = (const float*)d_in[3];
    const float* a1s  = (const float*)d_in[4];
    const float* a1d  = (const float*)d_in[5];
    const float* b1   = (const float*)d_in[6];
    const float* W2   = (const float*)d_in[7];
    const float* a2s  = (const float*)d_in[8];
    const float* a2d  = (const float*)d_in[9];
    const float* b2   = (const float*)d_in[10];
    const float* pW   = (const float*)d_in[11];
    const float* pb   = (const float*)d_in[12];
    const float* lng  = (const float*)d_in[13];
    const float* lnb  = (const float*)d_in[14];

    float* out_ge = (float*)d_out;                 // (32, 768)
    float* out_h2 = (float*)d_out + BG * 768;      // (16000, 128)

    char* w = (char*)d_ws;
    unsigned short* xb   = (unsigned short*)w;  w += (size_t)NN * IN_F * 2;
    unsigned short* W1b  = (unsigned short*)w;  w += (size_t)F1 * IN_F * 2;
    unsigned short* W2b  = (unsigned short*)w;  w += (size_t)F2 * F1 * 2;
    unsigned short* hbufb= (unsigned short*)w;  w += (size_t)NN * F1 * 2;
    unsigned short* h1b  = (unsigned short*)w;  w += (size_t)NN * F1 * 2;
    unsigned short* h2b  = (unsigned short*)w;  w += (size_t)NN * F2 * 2;
    // zeroed region: as1, ad1, as2, ad2, deg (contiguous, one memset)
    float* as1  = (float*)w;  w += (size_t)NN * H1C * 4;
    float* ad1  = (float*)w;  w += (size_t)NN * H1C * 4;
    float* as2  = (float*)w;  w += (size_t)NN * H2C * 4;
    float* ad2  = (float*)w;  w += (size_t)NN * H2C * 4;
    int* deg    = (int*)w;    w += (size_t)NN * 4;
    int* off    = (int*)w;    w += (size_t)(NN + 4) * 4;
    int* cursor = (int*)w;    w += (size_t)NN * 4;
    int* csr    = (int*)w;    w += (size_t)EP * 4;
    int* csrd   = (int*)w;    w += (size_t)EP * 4;
    float* el1  = (float*)w;  w += (size_t)EP * H1C * 4;
    float* el2  = (float*)w;  w += (size_t)EP * H2C * 4;

    hipMemsetAsync(as1, 0, (size_t)NN * (H1C + H1C + H2C + H2C + 1) * 4, stream);

    k_prep<<<NB_PREP, 256, 0, stream>>>(x, W1, W2, xb, W1b, W2b, ei, deg);
    k_scan<<<1, 1024, 0, stream>>>(deg, off, cursor);

    // GEMM1 (+ alpha1 epilogue) + CSR scatter as sequential tail blocks
    k_gemm1<<<G1_BLKS + NB_H, 256, 0, stream>>>(xb, W1b, hbufb, a1s, a1d, as1, ad1,
                                                ei, cursor, csr, csrd);
    k_el1<<<(EP + 255) / 256, 256, 0, stream>>>(csr, csrd, as1, ad1, el1);
    k_gat1<<<NN / 2, 256, 0, stream>>>(hbufb, el1, off, csr, b1, h1b);

    // GEMM2 (+ alpha2 epilogue), XCD-swizzled grid
    k_gemm2<<<512, 256, 0, stream>>>(h1b, W2b, h2b, a2s, a2d, as2, ad2);
    k_el2<<<(EP + 255) / 256, 256, 0, stream>>>(csr, csrd, as2, ad2, el2);
    k_gat2<<<NN / 4, 256, 0, stream>>>(h2b, el2, off, csr, b2, out_h2);

    k_proj_ln<<<BG, 1024, 0, stream>>>(out_h2, batch, pW, pb, lng, lnb, out_ge);
}